// Round 4
// baseline (5282.493 us; speedup 1.0000x reference)
//
#include <hip/hip_runtime.h>
#include <stdint.h>

// RNN_29102698398007 — B=64, T=512, D=H=1024.  Inputs fp32, output fp32.
//
//   gemm_xh : xh = X @ Kw -> Y fp32 (in place of output)           [1 launch]
//   swz     : W_rec fp32 -> d_ws bf16 frag order; zero flags       [1 launch]
//   scan_k  : ALL 512 steps in ONE persistent kernel.              [1 launch]
//     V4: 32 wgs x 512 thr = 4 row-groups x 8 col-groups.  Per step:
//       * h stored as relaxed AGENT-scope u64 WT stores (to MALL) in MFMA
//         frag order (as V3).
//       * per-WAVE flags (64 per row-group, value = step+1, monotone):
//         each wave signals after ITS OWN vmcnt(0) — no __syncthreads, no
//         atomic-RMW barrier, no tid0 serialization.
//       * readers poll all 64 flags with a wave-wide 64-lane relaxed load +
//         __all(); then read h via relaxed AGENT u64 loads (MALL-direct).
//         NO cache-wide acquire-inv -> Y/xh lines stay hot in local L2.
//       * Y fp32 store + next xh prefetch overlapped into the poll window.
// Fallback (ws too small): per-step launch path retained.

using short8 = __attribute__((ext_vector_type(8))) short;
using bf16x8 = __attribute__((ext_vector_type(8))) __bf16;
using f32x4  = __attribute__((ext_vector_type(4))) float;

typedef unsigned short     u16;
typedef unsigned int       u32;
typedef unsigned long long u64;
using u64x2 = __attribute__((ext_vector_type(2))) u64;

#define T_  512
#define H_  1024

__device__ __forceinline__ u16 f2bf(float f) {
    union { float f; u32 i; } v; v.f = f;
    u32 b = v.i + 0x7fffu + ((v.i >> 16) & 1u);   // RNE; finite values only
    return (u16)(b >> 16);
}
__device__ __forceinline__ f32x4 mfma_bf16_16x16x32(short8 a, short8 b, f32x4 c) {
    return __builtin_amdgcn_mfma_f32_16x16x32_bf16(
        __builtin_bit_cast(bf16x8, a), __builtin_bit_cast(bf16x8, b), c, 0, 0, 0);
}
__device__ __forceinline__ float sigmoidf(float z) {
    z = fminf(fmaxf(z, -30.f), 30.f);
    return 1.f / (1.f + __expf(-z));
}
__device__ __forceinline__ short8 cvt8(f32x4 a0, f32x4 a1) {
    short8 r;
    #pragma unroll
    for (int j = 0; j < 4; ++j) { r[j] = (short)f2bf(a0[j]); r[4 + j] = (short)f2bf(a1[j]); }
    return r;
}

// ---------------- k0: xh = X[32768,1024] @ Kw[1024,1024], fp32 -> fp32 ----------------
__global__ __launch_bounds__(256) void gemm_xh(const float* __restrict__ X,
                                               const float* __restrict__ Kw,
                                               float* __restrict__ Y)
{
    __shared__ alignas(16) u16 Bt[64][40];     // [n][k], k padded 32->40
    const int tid  = threadIdx.x;
    const int lane = tid & 63;
    const int wv   = tid >> 6;
    const int quad = lane >> 4;
    const int l16  = lane & 15;
    const int m0   = blockIdx.x * 64;
    const int n0   = blockIdx.y * 64;
    const int cB   = tid & 63;                 // staging: n within tile
    const int kg   = tid >> 6;                 // staging: k octet

    f32x4 acc[4] = {};

    for (int k0 = 0; k0 < H_; k0 += 32) {
        __syncthreads();
        short8 sv;
        #pragma unroll
        for (int jj = 0; jj < 8; ++jj)
            sv[jj] = (short)f2bf(Kw[(k0 + kg * 8 + jj) * H_ + n0 + cB]);
        *(short8*)&Bt[cB][kg * 8] = sv;
        __syncthreads();

        const f32x4* p = (const f32x4*)&X[(m0 + wv * 16 + l16) * H_ + k0 + quad * 8];
        short8 av = cvt8(p[0], p[1]);
        #pragma unroll
        for (int nt = 0; nt < 4; ++nt) {
            short8 bv = *(const short8*)&Bt[nt * 16 + l16][quad * 8];
            acc[nt] = mfma_bf16_16x16x32(av, bv, acc[nt]);
        }
    }
    #pragma unroll
    for (int nt = 0; nt < 4; ++nt)
        #pragma unroll
        for (int r = 0; r < 4; ++r)
            Y[(m0 + wv * 16 + quad * 4 + r) * H_ + n0 + nt * 16 + l16] = acc[nt][r];
}

// ---------------- k1: swizzle W_rec (fp32) into bf16 B-frag order; zero flags --------
// Wsw frag layout: [(c16*32 + kt)*64 + lane]*8, c16 = 16-col group [0,64)
__global__ __launch_bounds__(256) void swz(const float* __restrict__ Kr,
                                           u16* __restrict__ Wsw,
                                           u32* __restrict__ fl)
{
    const int t    = blockIdx.x * 256 + threadIdx.x;   // [0, 131072)
    if (fl && t < 256) fl[t] = 0;                      // reset 4x64 wave flags
    const int lane = t & 63;
    const int kt   = (t >> 6) & 31;
    const int wv   = (t >> 11) & 1;
    const int gj   = t >> 12;
    const int quad = lane >> 4;
    const int l16  = lane & 15;
    const int col  = gj * 32 + wv * 16 + l16;
    short8 sv;
    #pragma unroll
    for (int jj = 0; jj < 8; ++jj)
        sv[jj] = (short)f2bf(Kr[(kt * 32 + quad * 8 + jj) * H_ + col]);
    *(short8*)&Wsw[t * 8] = sv;
}

// ---------------- k2 (V4): persistent scan — 4 row-groups x 8 col-groups ----------------
// wg(rg,cg): rows [16rg,16rg+16) x cols [128cg,128cg+128). 8 waves, 16 cols/wave.
// h_s per-rg in MFMA frag order (32KB): element (batch b, col C) at u16 offset
//   (C>>5)*512 + (((C>>3)&3)*16 + b)*8 + (C&7).
// Sync: flag[rg][cg*8+wv] = s+1 (monotone), WT after wave's own vmcnt(0).
__global__ __launch_bounds__(512) void scan_k(float* __restrict__ Y,
                                              const u16* __restrict__ Wsw,
                                              u16* __restrict__ hb,
                                              u32* __restrict__ fl)
{
    const int tid  = threadIdx.x;
    const int lane = tid & 63;
    const int wv   = tid >> 6;          // 0..7
    const int quad = lane >> 4;
    const int l16  = lane & 15;
    const int rg   = blockIdx.x >> 3;   // 0..3  row-group
    const int cg   = blockIdx.x & 7;    // 0..7  col-group
    const int c16  = cg * 8 + wv;       // 16-col group id [0,64)

    // --- W fragments resident: 32 x short8 = 128 VGPRs/wave ---
    short8 wf[32];
    #pragma unroll
    for (int j2 = 0; j2 < 32; ++j2)
        wf[j2] = *(const short8*)&Wsw[(((unsigned)c16 * 32 + (unsigned)j2) * 64 + (unsigned)lane) * 8];

    // frag-order h buffers (u16): parity stride 65536 (128KB), rg stride 16384 (32KB)
    u16* const hbF0 = hb + rg * 16384;
    u16* const hbF1 = hb + 65536 + rg * 16384;

    u32* const flrg  = fl + rg * 64;            // this row-group's 64 wave flags
    u32* const flMine = flrg + c16;             // this wave's flag (written by lane 0)

    // writer slot: one u64 (4 bf16, cols C0..C0+3) per lane
    const int C0    = cg * 128 + wv * 16 + quad * 4;
    const int j2w   = C0 >> 5;
    const int quadp = (C0 >> 3) & 3;
    const int half  = (C0 >> 2) & 1;
    const int wOff  = j2w * 512 + (quadp * 16 + l16) * 8 + half * 4;   // u16 units

    // xh / Y address base: row = rg*16 + l16 (batch), cols C0..C0+3 (f32x4)
    const size_t rowBase = ((size_t)(rg * 16 + l16) * T_) * H_ + (size_t)C0;

    f32x4 xh = *(const f32x4*)&Y[rowBase];      // prefetch xh for s=0

    for (int s = 0; s < T_; ++s) {
        f32x4 a0 = {}, a1 = {}, a2 = {}, a3 = {};
        if (s > 0) {
            const u16* hp = ((s - 1) & 1) ? hbF1 : hbF0;
            const u64* ap = (const u64*)hp + (size_t)lane * 2;   // + j2*128
            #pragma unroll
            for (int j2 = 0; j2 < 32; ++j2) {
                u64x2 q;
                q[0] = __hip_atomic_load(ap + j2 * 128 + 0, __ATOMIC_RELAXED, __HIP_MEMORY_SCOPE_AGENT);
                q[1] = __hip_atomic_load(ap + j2 * 128 + 1, __ATOMIC_RELAXED, __HIP_MEMORY_SCOPE_AGENT);
                short8 av = __builtin_bit_cast(short8, q);
                switch (j2 & 3) {
                    case 0: a0 = mfma_bf16_16x16x32(wf[j2], av, a0); break;
                    case 1: a1 = mfma_bf16_16x16x32(wf[j2], av, a1); break;
                    case 2: a2 = mfma_bf16_16x16x32(wf[j2], av, a2); break;
                    default:a3 = mfma_bf16_16x16x32(wf[j2], av, a3); break;
                }
            }
        }

        f32x4 hv;
        #pragma unroll
        for (int r = 0; r < 4; ++r)
            hv[r] = sigmoidf((a0[r] + a1[r]) + (a2[r] + a3[r]) + xh[r]);

        // device-coherent h store: one relaxed agent-scope u64 (write-through to MALL)
        const u64 pk = (u64)f2bf(hv[0]) | ((u64)f2bf(hv[1]) << 16)
                     | ((u64)f2bf(hv[2]) << 32) | ((u64)f2bf(hv[3]) << 48);
        u16* const hc = (s & 1) ? hbF1 : hbF0;
        __hip_atomic_store((u64*)(hc + wOff), pk, __ATOMIC_RELAXED, __HIP_MEMORY_SCOPE_AGENT);

        if (s + 1 < T_) {
            asm volatile("s_waitcnt vmcnt(0)" ::: "memory");  // this wave's h at MALL
            if (lane == 0)                                     // per-wave release flag
                __hip_atomic_store(flMine, (u32)(s + 1), __ATOMIC_RELAXED, __HIP_MEMORY_SCOPE_AGENT);
            // overlapped with peers' flag propagation: fp32 Y store + next xh prefetch
            *(f32x4*)&Y[rowBase + (size_t)s * H_] = hv;
            xh = *(const f32x4*)&Y[rowBase + (size_t)(s + 1) * H_];
            // wave-wide poll: lane i watches flag i of this row-group
            const u32 tgt = (u32)(s + 1);
            for (;;) {
                u32 f = __hip_atomic_load(&flrg[lane], __ATOMIC_RELAXED, __HIP_MEMORY_SCOPE_AGENT);
                if (__all(f >= tgt)) break;
                __builtin_amdgcn_s_sleep(1);
            }
        } else {
            *(f32x4*)&Y[rowBase + (size_t)s * H_] = hv;
        }
    }
}

// ---------------- k2 (fallback): one scan step per launch ----------------
template<bool SW>
__global__ __launch_bounds__(128) void step_k(float* __restrict__ Y,
                                              const void* __restrict__ Wsrc,
                                              int s)
{
    const int tid  = threadIdx.x;
    const int lane = tid & 63;
    const int wv   = tid >> 6;
    const int quad = lane >> 4;
    const int l16  = lane & 15;
    const int gi   = blockIdx.x >> 5;
    const int gj   = blockIdx.x & 31;
    const int colBase = gj * 32 + wv * 16;

    f32x4 acc = {};
    if (s > 0) {
        const int abase = ((gi * 16 + l16) * T_ + (s - 1)) * H_;
        #pragma unroll 4
        for (int j2 = 0; j2 < 32; ++j2) {
            const f32x4* ap = (const f32x4*)&Y[abase + j2 * 32 + quad * 8];
            short8 av = cvt8(ap[0], ap[1]);
            short8 bv;
            if (SW) {
                bv = *(const short8*)&((const u16*)Wsrc)[(((gj * 2 + wv) * 32 + j2) * 64 + lane) * 8];
            } else {
                const float* Krf = (const float*)Wsrc;
                #pragma unroll
                for (int jj = 0; jj < 8; ++jj)
                    bv[jj] = (short)f2bf(Krf[(j2 * 32 + quad * 8 + jj) * H_ + colBase + l16]);
            }
            acc = mfma_bf16_16x16x32(av, bv, acc);
        }
    }
    #pragma unroll
    for (int r = 0; r < 4; ++r) {
        const int idx = ((gi * 16 + quad * 4 + r) * T_ + s) * H_ + colBase + l16;
        float z = acc[r] + Y[idx];
        Y[idx] = sigmoidf(z);
    }
}

extern "C" void kernel_launch(void* const* d_in, const int* in_sizes, int n_in,
                              void* d_out, int out_size, void* d_ws, size_t ws_size,
                              hipStream_t stream) {
    const float* X  = (const float*)d_in[0];   // x [64,512,1024] fp32
    const float* Kw = (const float*)d_in[1];   // kernel [1024,1024] fp32
    const float* Kr = (const float*)d_in[2];   // recurrent_kernel [1024,1024] fp32
    float* Y        = (float*)d_out;           // [64,512,1024] fp32 (xh, then h)

    gemm_xh<<<dim3(512, 16), dim3(256), 0, stream>>>(X, Kw, Y);

    // d_ws: [0,2MB) Wsw | [2MB,+256KB) h frag double buffer | +256KB: 4x64 u32 flags
    const size_t WSW_B  = (size_t)2 * 1024 * 1024;
    const size_t HB_B   = (size_t)2 * 64 * H_ * sizeof(u16);   // 256 KB
    const size_t needed = WSW_B + HB_B + 1024;

    if (ws_size >= needed) {
        u16* Wsw = (u16*)d_ws;
        u16* hbd = (u16*)((char*)d_ws + WSW_B);
        u32* fl  = (u32*)((char*)d_ws + WSW_B + HB_B);
        swz<<<dim3(512), dim3(256), 0, stream>>>(Kr, Wsw, fl);
        scan_k<<<dim3(32), dim3(512), 0, stream>>>(Y, Wsw, hbd, fl);
    } else if (ws_size >= WSW_B) {
        u16* Wsw = (u16*)d_ws;
        swz<<<dim3(512), dim3(256), 0, stream>>>(Kr, Wsw, (u32*)nullptr);
        for (int s = 0; s < T_; ++s)
            step_k<true><<<dim3(128), dim3(128), 0, stream>>>(Y, (const void*)Wsw, s);
    } else {
        for (int s = 0; s < T_; ++s)
            step_k<false><<<dim3(128), dim3(128), 0, stream>>>(Y, (const void*)Kr, s);
    }
}